// Round 5
// baseline (199.932 us; speedup 1.0000x reference)
//
#include <hip/hip_runtime.h>

#define D_IN   2304
#define D_SAE  2048
#define TL     24          // T*L
#define BATCH  32
#define K_TOP  128
#define NLAT   (TL * D_SAE)   // 49152
#define NBIN   8192
#define CAP    2048
#define KSPLIT 8
#define KS     (D_IN / KSPLIT)  // 288
#define BK     8
#define NCH    (KS / BK)        // 36

__device__ __forceinline__ void async_cp16(const float* g, float* l) {
    __builtin_amdgcn_global_load_lds(
        (const __attribute__((address_space(1))) unsigned int*)g,
        (__attribute__((address_space(3))) unsigned int*)l, 16, 0, 0);
}

// ---------------- encode ----------------
// grid (4, TL, KSPLIT), block 256 (4 waves). Block tile: 32 batches x 512 cols.
// Thread tile: 8 batches x 8 cols (acc = 64 VGPR). All LDS reads are b128:
// per 4k per thread: 8 x-b128 + 8 w-b128 = 256 B per 256 FMA = 1.0 B/FMA.
// Floors: LDS ~69 us, HBM ~76 us, VALU ~46 us. 768 blocks = 3/CU exactly.
__global__ __launch_bounds__(256, 3) void enc_kernel(const float* __restrict__ x,
                                                     const float* __restrict__ W,
                                                     float* __restrict__ part) {
    __shared__ float w_s[2][BK][512];     // 32 KB
    __shared__ float x_s[2][BATCH][BK];   // 2 KB (flat idx = b*8 + k)

    const int tid  = threadIdx.x;
    const int lane = tid & 63;
    const int wv   = tid >> 6;            // wave id = batch group (8 batches)
    const int tl   = blockIdx.y;
    const int ks   = blockIdx.z;
    const int col0 = blockIdx.x * 512;

    const float* Wbase = W + ((size_t)(tl * D_IN + ks * KS)) * D_SAE + col0;
    // x source for this lane: batch = lane>>1, k-offset = (lane&1)*4
    const float* xsrc = x + ((size_t)((lane >> 1) * TL + tl)) * D_IN
                      + ks * KS + (lane & 1) * 4;

    // stage chunk ch into buffer buf: per wave 4 w-gload16 (2 rows x 2 halves)
    // + 1 x-gload16 (redundant across waves, benign) = 5 vm ops.
#define STAGE(buf, ch)                                                          \
    do {                                                                        \
        const float* Wc = Wbase + (size_t)((ch) * BK) * D_SAE;                  \
        _Pragma("unroll")                                                       \
        for (int j = 0; j < 2; ++j) {                                           \
            int r = wv * 2 + j;                                                 \
            async_cp16(Wc + (size_t)r * D_SAE + lane * 4,       &w_s[buf][r][0]);   \
            async_cp16(Wc + (size_t)r * D_SAE + 256 + lane * 4, &w_s[buf][r][256]); \
        }                                                                       \
        async_cp16(xsrc + (ch) * BK, &x_s[buf][0][0]);                          \
    } while (0)

    float4 accA[8], accB[8];
#pragma unroll
    for (int j = 0; j < 8; ++j) {
        accA[j] = make_float4(0.f, 0.f, 0.f, 0.f);
        accB[j] = make_float4(0.f, 0.f, 0.f, 0.f);
    }

    STAGE(0, 0);

    int cur = 0;
    for (int ch = 0; ch < NCH; ++ch) {
        if (ch + 1 < NCH) {
            STAGE(cur ^ 1, ch + 1);                           // next chunk in flight
            asm volatile("s_waitcnt vmcnt(5)" ::: "memory");  // cur chunk's 5 landed
        } else {
            asm volatile("s_waitcnt vmcnt(0)" ::: "memory");
        }
        asm volatile("s_barrier" ::: "memory");               // all waves' cur landed

        const float(*ws)[512] = w_s[cur];
        const float(*xs)[BK]  = x_s[cur];
#pragma unroll
        for (int g = 0; g < 2; ++g) {                         // 2 groups of 4 k
            float4 wA[4], wB[4];
#pragma unroll
            for (int k = 0; k < 4; ++k) {
                wA[k] = *(const float4*)&ws[g * 4 + k][lane * 4];
                wB[k] = *(const float4*)&ws[g * 4 + k][256 + lane * 4];
            }
#pragma unroll
            for (int b = 0; b < 8; ++b) {
                float4 xv = *(const float4*)&xs[wv * 8 + b][g * 4];  // broadcast b128
                const float* xf = (const float*)&xv;
#pragma unroll
                for (int k = 0; k < 4; ++k) {
                    accA[b].x = fmaf(xf[k], wA[k].x, accA[b].x);
                    accA[b].y = fmaf(xf[k], wA[k].y, accA[b].y);
                    accA[b].z = fmaf(xf[k], wA[k].z, accA[b].z);
                    accA[b].w = fmaf(xf[k], wA[k].w, accA[b].w);
                    accB[b].x = fmaf(xf[k], wB[k].x, accB[b].x);
                    accB[b].y = fmaf(xf[k], wB[k].y, accB[b].y);
                    accB[b].z = fmaf(xf[k], wB[k].z, accB[b].z);
                    accB[b].w = fmaf(xf[k], wB[k].w, accB[b].w);
                }
            }
        }
        asm volatile("s_barrier" ::: "memory");               // safe to overwrite cur
        cur ^= 1;
    }
#undef STAGE

    float* pp = part + ((size_t)ks * BATCH + wv * 8) * NLAT
              + (size_t)tl * D_SAE + col0 + lane * 4;
#pragma unroll
    for (int j = 0; j < 8; ++j) {
        *(float4*)&pp[(size_t)j * NLAT]       = accA[j];
        *(float4*)&pp[(size_t)j * NLAT + 256] = accB[j];
    }
}

// ---------------- reduce partials + bias -> pre (float4) ----------------
__global__ void reduce_kernel(const float* __restrict__ part,
                              const float* __restrict__ b_enc,
                              float* __restrict__ pre) {
    int i = (blockIdx.x * blockDim.x + threadIdx.x) * 4;   // [0, BATCH*NLAT)
    const size_t S = (size_t)BATCH * NLAT;
    float4 v = *(const float4*)&b_enc[i & (D_SAE - 1)];
#pragma unroll
    for (int s = 0; s < KSPLIT; s++) {
        float4 p = *(const float4*)&part[i + s * S];
        v.x += p.x; v.y += p.y; v.z += p.z; v.w += p.w;
    }
    *(float4*)&pre[i] = v;
}

// ---------------- exact top-K per batch row; writes all of z; zeroes loss ----------------
__global__ __launch_bounds__(256) void topk_kernel(const float* __restrict__ pre,
                                                   int* __restrict__ sel_idx,
                                                   float* __restrict__ sel_val,
                                                   float* __restrict__ z,
                                                   float* __restrict__ loss) {
    const int b   = blockIdx.x;
    const int tid = threadIdx.x;
    __shared__ unsigned hist[NBIN];
    __shared__ unsigned cand_key[CAP];
    __shared__ int      cand_idx[CAP];
    __shared__ unsigned tsum[256];
    __shared__ unsigned suf[256];
    __shared__ int s_T, s_hi, s_ccnt, s_sel;

    const float* row  = pre + (size_t)b * NLAT;
    float*       zrow = z   + (size_t)b * NLAT;
    for (int i = tid; i < NBIN; i += 256) hist[i] = 0;
    if (tid == 0) { s_ccnt = 0; s_sel = 0; if (b == 0) *loss = 0.f; }
    __syncthreads();

    for (int i = 4 * tid; i < NLAT; i += 1024) {
        float4 v = *(const float4*)&row[i];
#pragma unroll
        for (int j = 0; j < 4; j++) {
            unsigned u   = __float_as_uint(((const float*)&v)[j]);
            unsigned key = u ^ ((u >> 31) ? 0xFFFFFFFFu : 0x80000000u);
            atomicAdd(&hist[key >> 19], 1u);
        }
    }
    __syncthreads();

    unsigned local = 0;
    const int base = tid * (NBIN / 256);
    for (int j = 0; j < NBIN / 256; j++) local += hist[base + j];
    tsum[tid] = local;
    __syncthreads();
    if (tid == 0) {                 // suffix-exclusive sums over 256 thread ranges
        unsigned run = 0;
        for (int t = 255; t >= 0; t--) { suf[t] = run; run += tsum[t]; }
    }
    __syncthreads();
    if (suf[tid] < K_TOP && suf[tid] + tsum[tid] >= K_TOP) {  // exactly one thread
        unsigned c = suf[tid];
        for (int j = NBIN / 256 - 1; j >= 0; j--) {
            int bin = base + j;
            if (c + hist[bin] >= K_TOP) { s_T = bin; s_hi = (int)c; break; }
            c += hist[bin];
        }
    }
    __syncthreads();

    const int T = s_T;
    for (int i = 4 * tid; i < NLAT; i += 1024) {
        float4 v = *(const float4*)&row[i];
#pragma unroll
        for (int j = 0; j < 4; j++) {
            float f      = ((const float*)&v)[j];
            unsigned u   = __float_as_uint(f);
            unsigned key = u ^ ((u >> 31) ? 0xFFFFFFFFu : 0x80000000u);
            int bin      = (int)(key >> 19);
            float rl     = fmaxf(f, 0.f);
            float zval   = 0.f;
            if (bin > T) {
                int p = atomicAdd(&s_sel, 1);
                sel_idx[b * K_TOP + p] = i + j;
                sel_val[b * K_TOP + p] = rl;
                zval = rl;
            } else if (bin == T) {
                int p = atomicAdd(&s_ccnt, 1);
                if (p < CAP) { cand_key[p] = key; cand_idx[p] = i + j; }
            }
            zrow[i + j] = zval;      // z only 4B-aligned in d_out -> scalar store
        }
    }
    __syncthreads();

    const int need = K_TOP - s_hi;
    const int nc   = min(s_ccnt, CAP);
    for (int c = tid; c < nc; c += 256) {
        unsigned kc = cand_key[c]; int ic = cand_idx[c];
        int rank = 0;
        for (int j = 0; j < nc; j++) {
            unsigned kj = cand_key[j]; int ij = cand_idx[j];
            rank += (kj > kc) || (kj == kc && ij < ic);   // ties -> lower index wins
        }
        if (rank < need) {
            int p = atomicAdd(&s_sel, 1);
            float rl = fmaxf(row[ic], 0.f);
            sel_idx[b * K_TOP + p] = ic;
            sel_val[b * K_TOP + p] = rl;
            zrow[ic] = rl;
        }
    }
}

// ---------------- sparse decode + x_hat + loss ----------------
__global__ __launch_bounds__(256) void dec_kernel(const float* __restrict__ Wd,
                                                  const float* __restrict__ b_dec,
                                                  const float* __restrict__ x,
                                                  const int* __restrict__ sel_idx,
                                                  const float* __restrict__ sel_val,
                                                  float* __restrict__ xhat,
                                                  float* __restrict__ loss) {
    const int tl = blockIdx.x, b = blockIdx.y, tid = threadIdx.x;
    float acc[9];
#pragma unroll
    for (int r = 0; r < 9; r++) acc[r] = b_dec[tl * D_IN + tid + r * 256];

    __shared__ int   s_idx[K_TOP];
    __shared__ float s_val[K_TOP];
    if (tid < K_TOP) { s_idx[tid] = sel_idx[b * K_TOP + tid];
                       s_val[tid] = sel_val[b * K_TOP + tid]; }
    __syncthreads();

    for (int j = 0; j < K_TOP; j++) {
        int f = s_idx[j];
        if ((f >> 11) == tl) {                 // D_SAE = 2048
            float v = s_val[j];
            const float* wrow = Wd + (size_t)f * D_IN;
#pragma unroll
            for (int r = 0; r < 9; r++)
                acc[r] = fmaf(v, wrow[tid + r * 256], acc[r]);
        }
    }

    const float* xr = x    + ((size_t)b * TL + tl) * D_IN;
    float*       xo = xhat + ((size_t)b * TL + tl) * D_IN;
    float lsum = 0.f;
#pragma unroll
    for (int r = 0; r < 9; r++) {
        float d = acc[r] - xr[tid + r * 256];
        xo[tid + r * 256] = acc[r];
        lsum += d * d;
    }
    __shared__ float red[256];
    red[tid] = lsum; __syncthreads();
    for (int s = 128; s > 0; s >>= 1) {
        if (tid < s) red[tid] += red[tid + s];
        __syncthreads();
    }
    if (tid == 0) atomicAdd(loss, red[0] * (1.0f / (BATCH * TL)));
}

extern "C" void kernel_launch(void* const* d_in, const int* in_sizes, int n_in,
                              void* d_out, int out_size, void* d_ws, size_t ws_size,
                              hipStream_t stream) {
    const float* x     = (const float*)d_in[0];
    const float* W_enc = (const float*)d_in[1];
    const float* W_dec = (const float*)d_in[2];
    const float* b_enc = (const float*)d_in[3];
    const float* b_dec = (const float*)d_in[4];

    float* out  = (float*)d_out;
    float* loss = out;
    float* xhat = out + 1;
    float* z    = out + 1 + (size_t)BATCH * TL * D_IN;

    const size_t S = (size_t)BATCH * NLAT;
    float* part    = (float*)d_ws;
    float* pre     = part + (size_t)KSPLIT * S;
    int*   sel_idx = (int*)(pre + S);
    float* sel_val = (float*)(sel_idx + BATCH * K_TOP);

    enc_kernel<<<dim3(4, TL, KSPLIT), 256, 0, stream>>>(x, W_enc, part);
    reduce_kernel<<<(int)(S / 1024), 256, 0, stream>>>(part, b_enc, pre);
    topk_kernel<<<BATCH, 256, 0, stream>>>(pre, sel_idx, sel_val, z, loss);
    dec_kernel<<<dim3(TL, BATCH), 256, 0, stream>>>(W_dec, b_dec, x, sel_idx, sel_val,
                                                    xhat, loss);
}